// Round 5
// baseline (210.285 us; speedup 1.0000x reference)
//
#include <hip/hip_runtime.h>

#define ROWS 1048576
#define BINS 17
#define RPB 64                  // rows per block = threads per block (1 wave)
#define NBLK (ROWS / RPB)       // 16384 blocks
#define GPB (RPB / 4)           // 16 conv groups per block
#define CONV_N 33               // 2*BINS - 1

// One wave per block. Single 4352B row buffer staged twice (pred then soft;
// both tiles' global loads prefetched to regs first), separate 2112B ratio
// buffer -> 6464B LDS/block (~24-block LDS cap). Single-wave blocks:
// __syncthreads lowers to s_waitcnt only. VALU diet vs round 4:
//   - KL loop fused:  kl = D/seb - log(seb) + log(sea),  D = sum e^bj (bj-aj)
//   - ts-loop exps kept in ey[17] and reused for the softmax write
//   => 51 exps/row instead of 85.
// Dual accumulator chains halve dependent-reduction depth.
template <bool PART>
__global__ __launch_bounds__(64, 4) void kd_main(
    const float* __restrict__ pred,
    const float* __restrict__ soft,
    const float* __restrict__ weight,
    float* __restrict__ out,
    float* __restrict__ ws)
{
    __shared__ float sA[RPB * BINS];   // 4352 B: pred tile -> soft tile -> softmax
    __shared__ float sR[GPB * CONV_N]; // 2112 B: ratio staging
    const int tid = threadIdx.x;
    const long long base = (long long)blockIdx.x * (RPB * BINS);

    // ---- prefetch both tiles (272 float4 each) into registers ----
    const float4* p4 = reinterpret_cast<const float4*>(pred + base);
    const float4* q4 = reinterpret_cast<const float4*>(soft + base);
    float4 P[5] = {}, Q[5] = {};
#pragma unroll
    for (int k = 0; k < 4; ++k) {
        P[k] = p4[k * 64 + tid];
        Q[k] = q4[k * 64 + tid];
    }
    if (tid < 16) { P[4] = p4[256 + tid]; Q[4] = q4[256 + tid]; }
    const float w = weight[blockIdx.x * RPB + tid];

    float4* a4 = reinterpret_cast<float4*>(sA);
#pragma unroll
    for (int k = 0; k < 4; ++k) a4[k * 64 + tid] = P[k];
    if (tid < 16) a4[256 + tid] = P[4];
    __syncthreads();

    // ---- x phase (pred): stats + keep row in regs ----
    float x[BINS];
#pragma unroll
    for (int j = 0; j < BINS; ++j) x[j] = sA[tid * BINS + j];

    float s0 = 0.f, s1 = 0.f, m0 = -1e30f, m1 = -1e30f;
#pragma unroll
    for (int j = 0; j < 16; j += 2) {
        s0 += x[j];     m0 = fmaxf(m0, x[j]);
        s1 += x[j + 1]; m1 = fmaxf(m1, x[j + 1]);
    }
    const float mx  = (s0 + s1 + x[16]) * (1.0f / BINS);
    const float xmx = fmaxf(fmaxf(m0, m1), x[16]);

    float v0 = 0.f, v1 = 0.f;
#pragma unroll
    for (int j = 0; j < 16; j += 2) {
        const float d0 = x[j] - mx;     v0 = fmaf(d0, d0, v0);
        const float d1 = x[j + 1] - mx; v1 = fmaf(d1, d1, v1);
    }
    const float dx16 = x[16] - mx;
    const float vx = fmaf(dx16, dx16, v0 + v1);
    const float invsx = 0.1f / (1e-7f + sqrtf(vx * (1.0f / (BINS - 1))));
    const float amax = (xmx - mx) * invsx;
    const float ca = -mx * invsx - amax;   // aj = fmaf(x, invsx, ca)

    __syncthreads();  // all x reads done -> safe to overwrite with soft
#pragma unroll
    for (int k = 0; k < 4; ++k) a4[k * 64 + tid] = Q[k];
    if (tid < 16) a4[256 + tid] = Q[4];
    __syncthreads();

    // ---- y phase (soft): stats ----
    float y[BINS];
#pragma unroll
    for (int j = 0; j < BINS; ++j) y[j] = sA[tid * BINS + j];

    s0 = 0.f; s1 = 0.f; m0 = -1e30f; m1 = -1e30f;
#pragma unroll
    for (int j = 0; j < 16; j += 2) {
        s0 += y[j];     m0 = fmaxf(m0, y[j]);
        s1 += y[j + 1]; m1 = fmaxf(m1, y[j + 1]);
    }
    const float my  = (s0 + s1 + y[16]) * (1.0f / BINS);
    const float ymx = fmaxf(fmaxf(m0, m1), y[16]);

    v0 = 0.f; v1 = 0.f;
#pragma unroll
    for (int j = 0; j < 16; j += 2) {
        const float d0 = y[j] - my;     v0 = fmaf(d0, d0, v0);
        const float d1 = y[j + 1] - my; v1 = fmaf(d1, d1, v1);
    }
    const float dy16 = y[16] - my;
    const float vy = fmaf(dy16, dy16, v0 + v1);
    const float invsy = 0.1f / (1e-7f + sqrtf(vy * (1.0f / (BINS - 1))));
    const float bmax = (ymx - my) * invsy;
    const float cb = -my * invsy - bmax;   // bj = fmaf(y, invsy, cb)

    // ---- single fused loop: sea, seb, D, ts (+ey kept) ----
    float ey[BINS];
    float sea0 = 0.f, sea1 = 0.f, seb0 = 0.f, seb1 = 0.f;
    float ts0 = 0.f, ts1 = 0.f, D0 = 0.f, D1 = 0.f;
#pragma unroll
    for (int j = 0; j < BINS; ++j) {
        const float aj = fmaf(x[j], invsx, ca);
        const float bj = fmaf(y[j], invsy, cb);
        const float eb = __expf(bj);
        const float ea = __expf(aj);
        ey[j] = __expf(y[j] - ymx);
        if (j & 1) { seb1 += eb; sea1 += ea; ts1 += ey[j]; D1 = fmaf(eb, bj - aj, D1); }
        else       { seb0 += eb; sea0 += ea; ts0 += ey[j]; D0 = fmaf(eb, bj - aj, D0); }
    }
    const float seb = seb0 + seb1;
    const float sea = sea0 + sea1;
    const float ts  = ts0 + ts1;
    const float kl  = (D0 + D1) / seb - __logf(seb) + __logf(sea);
    const float invts = 1.0f / ts;

    // target softmax -> own row of sA (soft tile fully consumed into regs)
#pragma unroll
    for (int j = 0; j < BINS; ++j)
        sA[tid * BINS + j] = ey[j] * invts;

    // ---- wave reduce kl & weight ----
    float k2 = kl, w2 = w;
#pragma unroll
    for (int off = 32; off >= 1; off >>= 1) {
        k2 += __shfl_down(k2, off, 64);
        w2 += __shfl_down(w2, off, 64);
    }

    __syncthreads();  // softmax rows visible (single wave: waitcnt only)

    // ---- conv: tid<32. even lane: left*right (rows 4g+2,3); odd: top*bottom
    //      (rows 4g+0,1). Row pair = 34 contiguous floats, 8B-aligned. ----
    if (tid < 2 * GPB) {
        const int g = tid >> 1;
        const int R = 4 * g + ((tid & 1) ? 0 : 2);
        float f[2 * BINS];
        const float2* pr = reinterpret_cast<const float2*>(&sA[R * BINS]);
#pragma unroll
        for (int i = 0; i < BINS; ++i) {
            const float2 v = pr[i];
            f[2 * i] = v.x; f[2 * i + 1] = v.y;
        }
        float accv[CONV_N];
#pragma unroll
        for (int j = 0; j < CONV_N; ++j) accv[j] = 0.f;
#pragma unroll
        for (int k = 0; k < BINS; ++k)
#pragma unroll
            for (int m = 0; m < BINS; ++m)
                accv[k + m] = fmaf(f[k], f[BINS + m], accv[k + m]);

        // adjacent-lane exchange: even lane = slr, odd lane = stb
#pragma unroll
        for (int j = 0; j < CONV_N; ++j) {
            const float o = __shfl_down(accv[j], 1, 64);
            if ((tid & 1) == 0)
                sR[g * CONV_N + j] = accv[j] / (o + 1e-8f);
        }
    }
    __syncthreads();

    // ---- coalesced store of the 528 ratio floats ----
    const long long ob = 1 + (long long)blockIdx.x * (GPB * CONV_N);
#pragma unroll
    for (int i = 0; i < 8; ++i)
        out[ob + i * 64 + tid] = sR[i * 64 + tid];
    if (tid < 16) out[ob + 512 + tid] = sR[512 + tid];

    // ---- scalar-path partials ----
    if (tid == 0) {
        if (PART) {
            ws[blockIdx.x]        = k2;
            ws[NBLK + blockIdx.x] = w2;
        } else {
            atomicAdd(&ws[0], k2);
            atomicAdd(&ws[1], w2);
        }
    }
}

template <bool PART>
__global__ __launch_bounds__(1024) void kd_reduce(
    const float* __restrict__ ws, float* __restrict__ out)
{
    if (!PART) {
        if (threadIdx.x == 0)
            out[0] = 100.0f * (ws[0] * (1.0f / ROWS)) * (ws[1] * (1.0f / ROWS));
        return;
    }
    __shared__ float red[32];
    const int tid = threadIdx.x;
    const float4* k4 = reinterpret_cast<const float4*>(ws);          // 4096 f4
    const float4* w4 = reinterpret_cast<const float4*>(ws + NBLK);   // 4096 f4
    float ks = 0.f, wsum = 0.f;
#pragma unroll
    for (int i = 0; i < 4; ++i) {
        const float4 a = k4[i * 1024 + tid];
        const float4 b = w4[i * 1024 + tid];
        ks += (a.x + a.y) + (a.z + a.w);
        wsum += (b.x + b.y) + (b.z + b.w);
    }
#pragma unroll
    for (int off = 32; off >= 1; off >>= 1) {
        ks += __shfl_down(ks, off, 64);
        wsum += __shfl_down(wsum, off, 64);
    }
    if ((tid & 63) == 0) {
        red[(tid >> 6) * 2 + 0] = ks;
        red[(tid >> 6) * 2 + 1] = wsum;
    }
    __syncthreads();
    if (tid == 0) {
        float K = 0.f, W = 0.f;
#pragma unroll
        for (int i = 0; i < 16; ++i) { K += red[2 * i]; W += red[2 * i + 1]; }
        out[0] = 100.0f * (K * (1.0f / ROWS)) * (W * (1.0f / ROWS));
    }
}

extern "C" void kernel_launch(void* const* d_in, const int* in_sizes, int n_in,
                              void* d_out, int out_size, void* d_ws, size_t ws_size,
                              hipStream_t stream)
{
    const float* pred   = (const float*)d_in[0];
    const float* soft   = (const float*)d_in[1];
    const float* weight = (const float*)d_in[2];
    float* out = (float*)d_out;
    float* ws  = (float*)d_ws;

    if (ws_size >= (size_t)(2 * NBLK) * sizeof(float)) {
        kd_main<true><<<NBLK, RPB, 0, stream>>>(pred, soft, weight, out, ws);
        kd_reduce<true><<<1, 1024, 0, stream>>>(ws, out);
    } else {
        hipMemsetAsync(ws, 0, 2 * sizeof(float), stream);
        kd_main<false><<<NBLK, RPB, 0, stream>>>(pred, soft, weight, out, ws);
        kd_reduce<false><<<1, 1024, 0, stream>>>(ws, out);
    }
}

// Round 6
// 184.343 us; speedup vs baseline: 1.1407x; 1.1407x over previous
//
#include <hip/hip_runtime.h>

#define ROWS 1048576
#define BINS 17
#define RPB 64                  // rows per block = threads per block (1 wave)
#define NBLK (ROWS / RPB)       // 16384 blocks
#define GPB (RPB / 4)           // 16 conv groups per block
#define CONV_N 33               // 2*BINS - 1

// One wave per block, dual LDS tiles (round-4 staging: load->store immediately,
// nothing held across phases -- round-5's register prefetch of both tiles
// spilled to scratch: WRITE_SIZE 35->211 MB). Keeps round-5's VALU diet:
//   - fused KL: kl = D/seb - log(seb) + log(sea), D = sum e^bj (bj - aj)
//   - ey[17] kept in regs and reused for the softmax write (51 exps/row)
//   - dual accumulator chains, fmaf-folded normalize constants.
template <bool PART>
__global__ __launch_bounds__(64, 4) void kd_main(
    const float* __restrict__ pred,
    const float* __restrict__ soft,
    const float* __restrict__ weight,
    float* __restrict__ out,
    float* __restrict__ ws)
{
    __shared__ float sA[RPB * BINS];  // pred tile -> target softmax
    __shared__ float sB[RPB * BINS];  // soft tile -> ratio restage
    const int tid = threadIdx.x;
    const long long base = (long long)blockIdx.x * (RPB * BINS);

    // ---- coalesced staging: 272 float4 per tile; store immediately ----
    const float4* p4 = reinterpret_cast<const float4*>(pred + base);
    const float4* q4 = reinterpret_cast<const float4*>(soft + base);
    float4* a4 = reinterpret_cast<float4*>(sA);
    float4* b4 = reinterpret_cast<float4*>(sB);
#pragma unroll
    for (int k = 0; k < 4; ++k) {
        a4[k * 64 + tid] = p4[k * 64 + tid];
        b4[k * 64 + tid] = q4[k * 64 + tid];
    }
    if (tid < 16) {
        a4[256 + tid] = p4[256 + tid];
        b4[256 + tid] = q4[256 + tid];
    }
    const float w = weight[blockIdx.x * RPB + tid];
    __syncthreads();

    // ---- per-row stats (row = tid); stride 17 (odd) -> 2-way alias, free ----
    float x[BINS], y[BINS];
#pragma unroll
    for (int j = 0; j < BINS; ++j) {
        x[j] = sA[tid * BINS + j];
        y[j] = sB[tid * BINS + j];
    }

    float sx0 = 0.f, sx1 = 0.f, mx0 = -1e30f, mx1 = -1e30f;
    float sy0 = 0.f, sy1 = 0.f, my0 = -1e30f, my1 = -1e30f;
#pragma unroll
    for (int j = 0; j < 16; j += 2) {
        sx0 += x[j];     mx0 = fmaxf(mx0, x[j]);
        sx1 += x[j + 1]; mx1 = fmaxf(mx1, x[j + 1]);
        sy0 += y[j];     my0 = fmaxf(my0, y[j]);
        sy1 += y[j + 1]; my1 = fmaxf(my1, y[j + 1]);
    }
    const float mx  = (sx0 + sx1 + x[16]) * (1.0f / BINS);
    const float my  = (sy0 + sy1 + y[16]) * (1.0f / BINS);
    const float xmx = fmaxf(fmaxf(mx0, mx1), x[16]);
    const float ymx = fmaxf(fmaxf(my0, my1), y[16]);

    float vx0 = 0.f, vx1 = 0.f, vy0 = 0.f, vy1 = 0.f;
#pragma unroll
    for (int j = 0; j < 16; j += 2) {
        const float dx0 = x[j] - mx;     vx0 = fmaf(dx0, dx0, vx0);
        const float dx1 = x[j + 1] - mx; vx1 = fmaf(dx1, dx1, vx1);
        const float dy0 = y[j] - my;     vy0 = fmaf(dy0, dy0, vy0);
        const float dy1 = y[j + 1] - my; vy1 = fmaf(dy1, dy1, vy1);
    }
    const float dx16 = x[16] - mx;
    const float dy16 = y[16] - my;
    const float vx = fmaf(dx16, dx16, vx0 + vx1);
    const float vy = fmaf(dy16, dy16, vy0 + vy1);

    // (x - mean)/(eps + std_ddof1) / T : fold 1/T into positive scale
    const float invsx = 0.1f / (1e-7f + sqrtf(vx * (1.0f / (BINS - 1))));
    const float invsy = 0.1f / (1e-7f + sqrtf(vy * (1.0f / (BINS - 1))));
    const float ca = -mx * invsx - (xmx - mx) * invsx;  // aj = fmaf(x,invsx,ca)
    const float cb = -my * invsy - (ymx - my) * invsy;  // bj = fmaf(y,invsy,cb)

    // ---- single fused loop: sea, seb, D, ts (+ey kept for softmax) ----
    float ey[BINS];
    float sea0 = 0.f, sea1 = 0.f, seb0 = 0.f, seb1 = 0.f;
    float ts0 = 0.f, ts1 = 0.f, D0 = 0.f, D1 = 0.f;
#pragma unroll
    for (int j = 0; j < BINS; ++j) {
        const float aj = fmaf(x[j], invsx, ca);
        const float bj = fmaf(y[j], invsy, cb);
        const float ea = __expf(aj);
        const float eb = __expf(bj);
        ey[j] = __expf(y[j] - ymx);
        if (j & 1) { sea1 += ea; seb1 += eb; ts1 += ey[j]; D1 = fmaf(eb, bj - aj, D1); }
        else       { sea0 += ea; seb0 += eb; ts0 += ey[j]; D0 = fmaf(eb, bj - aj, D0); }
    }
    const float sea = sea0 + sea1;
    const float seb = seb0 + seb1;
    const float ts  = ts0 + ts1;
    const float kl  = (D0 + D1) / seb - __logf(seb) + __logf(sea);
    const float invts = 1.0f / ts;

    // target softmax -> overwrite OWN row of sA (own-row, no barrier needed)
#pragma unroll
    for (int j = 0; j < BINS; ++j)
        sA[tid * BINS + j] = ey[j] * invts;

    // ---- wave reduce kl & weight ----
    float k2 = kl, w2 = w;
#pragma unroll
    for (int off = 32; off >= 1; off >>= 1) {
        k2 += __shfl_down(k2, off, 64);
        w2 += __shfl_down(w2, off, 64);
    }

    __syncthreads();  // softmax rows visible; sB reads retired (single wave)

    float* sR = sB;  // soft tile dead; reuse as ratio staging (528 floats)

    // ---- conv: tid<32. even lane: left*right (rows 4g+2,3); odd: top*bottom
    //      (rows 4g+0,1). Row pair = 34 contiguous floats, 8B-aligned. ----
    if (tid < 2 * GPB) {
        const int g = tid >> 1;
        const int R = 4 * g + ((tid & 1) ? 0 : 2);
        float f[2 * BINS];
        const float2* pr = reinterpret_cast<const float2*>(&sA[R * BINS]);
#pragma unroll
        for (int i = 0; i < BINS; ++i) {
            const float2 v = pr[i];
            f[2 * i] = v.x; f[2 * i + 1] = v.y;
        }
        float accv[CONV_N];
#pragma unroll
        for (int j = 0; j < CONV_N; ++j) accv[j] = 0.f;
#pragma unroll
        for (int k = 0; k < BINS; ++k)
#pragma unroll
            for (int m = 0; m < BINS; ++m)
                accv[k + m] = fmaf(f[k], f[BINS + m], accv[k + m]);

        // adjacent-lane exchange: even lane = slr, odd lane = stb
#pragma unroll
        for (int j = 0; j < CONV_N; ++j) {
            const float o = __shfl_down(accv[j], 1, 64);
            if ((tid & 1) == 0)
                sR[g * CONV_N + j] = accv[j] / (o + 1e-8f);
        }
    }
    __syncthreads();

    // ---- coalesced store of the 528 ratio floats ----
    const long long ob = 1 + (long long)blockIdx.x * (GPB * CONV_N);
#pragma unroll
    for (int i = 0; i < 8; ++i)
        out[ob + i * 64 + tid] = sR[i * 64 + tid];
    if (tid < 16) out[ob + 512 + tid] = sR[512 + tid];

    // ---- scalar-path partials ----
    if (tid == 0) {
        if (PART) {
            ws[blockIdx.x]        = k2;
            ws[NBLK + blockIdx.x] = w2;
        } else {
            atomicAdd(&ws[0], k2);
            atomicAdd(&ws[1], w2);
        }
    }
}

template <bool PART>
__global__ __launch_bounds__(1024) void kd_reduce(
    const float* __restrict__ ws, float* __restrict__ out)
{
    if (!PART) {
        if (threadIdx.x == 0)
            out[0] = 100.0f * (ws[0] * (1.0f / ROWS)) * (ws[1] * (1.0f / ROWS));
        return;
    }
    __shared__ float red[32];
    const int tid = threadIdx.x;
    const float4* k4 = reinterpret_cast<const float4*>(ws);          // 4096 f4
    const float4* w4 = reinterpret_cast<const float4*>(ws + NBLK);   // 4096 f4
    float ks = 0.f, wsum = 0.f;
#pragma unroll
    for (int i = 0; i < 4; ++i) {
        const float4 a = k4[i * 1024 + tid];
        const float4 b = w4[i * 1024 + tid];
        ks += (a.x + a.y) + (a.z + a.w);
        wsum += (b.x + b.y) + (b.z + b.w);
    }
#pragma unroll
    for (int off = 32; off >= 1; off >>= 1) {
        ks += __shfl_down(ks, off, 64);
        wsum += __shfl_down(wsum, off, 64);
    }
    if ((tid & 63) == 0) {
        red[(tid >> 6) * 2 + 0] = ks;
        red[(tid >> 6) * 2 + 1] = wsum;
    }
    __syncthreads();
    if (tid == 0) {
        float K = 0.f, W = 0.f;
#pragma unroll
        for (int i = 0; i < 16; ++i) { K += red[2 * i]; W += red[2 * i + 1]; }
        out[0] = 100.0f * (K * (1.0f / ROWS)) * (W * (1.0f / ROWS));
    }
}

extern "C" void kernel_launch(void* const* d_in, const int* in_sizes, int n_in,
                              void* d_out, int out_size, void* d_ws, size_t ws_size,
                              hipStream_t stream)
{
    const float* pred   = (const float*)d_in[0];
    const float* soft   = (const float*)d_in[1];
    const float* weight = (const float*)d_in[2];
    float* out = (float*)d_out;
    float* ws  = (float*)d_ws;

    if (ws_size >= (size_t)(2 * NBLK) * sizeof(float)) {
        kd_main<true><<<NBLK, RPB, 0, stream>>>(pred, soft, weight, out, ws);
        kd_reduce<true><<<1, 1024, 0, stream>>>(ws, out);
    } else {
        hipMemsetAsync(ws, 0, 2 * sizeof(float), stream);
        kd_main<false><<<NBLK, RPB, 0, stream>>>(pred, soft, weight, out, ws);
        kd_reduce<false><<<1, 1024, 0, stream>>>(ws, out);
    }
}